// Round 12
// baseline (694.989 us; speedup 1.0000x reference)
//
#include <hip/hip_runtime.h>
#include <hip/hip_bf16.h>

#define SS 2048
#define BB 16
#define DD 512

typedef __attribute__((ext_vector_type(4))) float f32x4;
typedef __attribute__((ext_vector_type(8))) short bf16x8;
typedef __attribute__((ext_vector_type(4))) unsigned short us4;
typedef unsigned short us;

#define MFMA16(a,b,c) __builtin_amdgcn_mfma_f32_16x16x32_bf16((a),(b),(c),0,0,0)
#define BAR() __builtin_amdgcn_s_barrier()
#define WAITV(n) asm volatile("s_waitcnt vmcnt(" #n ")" ::: "memory")
#define WAITL()  asm volatile("s_waitcnt lgkmcnt(0)" ::: "memory")

__device__ __forceinline__ unsigned short f2b(float f) {
    union { float f; unsigned u; } v; v.f = f;
    unsigned r = v.u + 0x7FFFu + ((v.u >> 16) & 1u);
    return (unsigned short)(r >> 16);
}

// 256B-row LDS tile, 4-bit XOR swizzle (16-slot spread)
__device__ __forceinline__ bf16x8 ldfrag8(const us* base, int row, int kelem) {
    int off = (row << 8) + (kelem << 1);
    off ^= (row & 15) << 4;
    return *(const bf16x8*)((const char*)base + off);
}
// 128B-row rows (k_gemm + XT chunks + Pb)
__device__ __forceinline__ bf16x8 ldfrag(const us* base, int row, int kelem, int rowshift) {
    int off = (row << rowshift) + (kelem << 1);
    off ^= (row & 7) << 4;
    return *(const bf16x8*)((const char*)base + off);
}

__device__ __forceinline__ void gl16(const void* g, void* l) {
    __builtin_amdgcn_global_load_lds(
        (const __attribute__((address_space(1))) unsigned*)g,
        (__attribute__((address_space(3))) unsigned*)l, 16, 0, 0);
}

// ---------------------------------------------------------------------------
// Prep: seq [S][B][D] fp32 -> Xb [B][S][D] bf16 and Xbt [B][D][S] bf16.
// ---------------------------------------------------------------------------
__global__ __launch_bounds__(256) void k_prep_x(const float* __restrict__ seq,
        us* __restrict__ Xb, us* __restrict__ Xbt) {
    __shared__ __align__(16) char L[64 * 128];
    const int tid = threadIdx.x;
    const int d0 = blockIdx.x * 64, s0 = blockIdx.y * 64, b = blockIdx.z;
    {
        int r = tid >> 2, seg = (tid & 3) * 16;
        const float* src = seq + (size_t)(s0 + r) * (BB * DD) + (size_t)b * DD + d0 + seg;
        __align__(16) us vals[16];
        #pragma unroll
        for (int q = 0; q < 4; ++q) {
            f32x4 v = *(const f32x4*)(src + q * 4);
            vals[q*4+0] = f2b(v.x); vals[q*4+1] = f2b(v.y);
            vals[q*4+2] = f2b(v.z); vals[q*4+3] = f2b(v.w);
        }
        us* xo = Xb + ((size_t)b * SS + s0 + r) * DD + d0 + seg;
        *(bf16x8*)xo       = *(bf16x8*)&vals[0];
        *(bf16x8*)(xo + 8) = *(bf16x8*)&vals[8];
        #pragma unroll
        for (int j = 0; j < 16; ++j) {
            int d = seg + j;
            int addr = (d * 128 + r * 2) ^ ((d & 7) << 4);
            *(us*)(L + addr) = vals[j];
        }
    }
    __syncthreads();
    {
        int d = tid >> 2, sseg = (tid & 3) * 16;
        int c = (d & 7) << 4;
        int base = d * 128 + sseg * 2;
        bf16x8 h0 = *(bf16x8*)(L + (base ^ c));
        bf16x8 h1 = *(bf16x8*)(L + ((base + 16) ^ c));
        us* o = Xbt + ((size_t)b * DD + d0 + d) * SS + s0 + sseg;
        *(bf16x8*)o       = h0;
        *(bf16x8*)(o + 8) = h1;
    }
}

// ---------------------------------------------------------------------------
// Gt[p][i] = (1/sqrt(D)) * sum_a Wv[a,i] * Wq[a,p]
// ---------------------------------------------------------------------------
__global__ __launch_bounds__(256) void k_prepG(const float* __restrict__ Wv,
        const float* __restrict__ Wq, us* __restrict__ Gt) {
    __shared__ float Sq[32][64], Sv[32][64];
    const int tid = threadIdx.x;
    const int p0 = blockIdx.x * 64, i0 = blockIdx.y * 64;
    const int tp = tid & 15, ti = tid >> 4;
    float acc[4][4] = {};
    for (int a0 = 0; a0 < DD; a0 += 32) {
        #pragma unroll
        for (int j = 0; j < 2; ++j) {
            int slot = tid + j * 256;
            int row = slot >> 4, c4 = (slot & 15) * 4;
            *(f32x4*)&Sq[row][c4] = *(const f32x4*)(Wq + (size_t)(a0 + row) * DD + p0 + c4);
            *(f32x4*)&Sv[row][c4] = *(const f32x4*)(Wv + (size_t)(a0 + row) * DD + i0 + c4);
        }
        __syncthreads();
        for (int a = 0; a < 32; ++a) {
            f32x4 q = *(f32x4*)&Sq[a][tp * 4];
            f32x4 v = *(f32x4*)&Sv[a][ti * 4];
            #pragma unroll
            for (int x = 0; x < 4; ++x)
                #pragma unroll
                for (int y = 0; y < 4; ++y)
                    acc[x][y] += q[x] * v[y];
        }
        __syncthreads();
    }
    const float sc = 0.044194173824159216f;
    #pragma unroll
    for (int x = 0; x < 4; ++x)
        #pragma unroll
        for (int y = 0; y < 4; ++y)
            Gt[(size_t)(p0 + tp * 4 + x) * DD + i0 + ti * 4 + y] = f2b(acc[x][y] * sc);
}

// u[p] = (1/sqrt(D)) * sum_a bv[a] * Wq[a,p]
__global__ __launch_bounds__(512) void k_prepU(const float* __restrict__ Wq,
        const float* __restrict__ bv, float* __restrict__ u) {
    int p = threadIdx.x;
    float s = 0.f;
    for (int a0 = 0; a0 < DD; a0 += 8) {
        #pragma unroll
        for (int j = 0; j < 8; ++j)
            s += bv[a0 + j] * Wq[(size_t)(a0 + j) * DD + p];
    }
    u[p] = s * 0.044194173824159216f;
}

__global__ void k_prepW(const float* __restrict__ Wk, us* __restrict__ Wkb) {
    int i = (blockIdx.x * 256 + threadIdx.x) * 4;
    f32x4 v = *(const f32x4*)(Wk + i);
    us4 o; o.x = f2b(v.x); o.y = f2b(v.y); o.z = f2b(v.z); o.w = f2b(v.w);
    *(us4*)(Wkb + i) = o;
}

// ---------------------------------------------------------------------------
// bf16 GEMM: C[row,n] = sum_k A[row,k]*Bm[n,k] + bias[n]
// ---------------------------------------------------------------------------
template<int OUTMODE>
__global__ __launch_bounds__(256, 2) void k_gemm(
        const us* __restrict__ A, const us* __restrict__ Bm,
        const float* __restrict__ bias, void* __restrict__ outp) {
    __shared__ __align__(16) us As[2][128 * 64];
    __shared__ __align__(16) us Bs[2][128 * 64];
    const int tid = threadIdx.x;
    const int lane = tid & 63;
    const int w = tid >> 6;
    const int wr = w >> 1, wc = w & 1;
    const int l15 = lane & 15, lg = lane >> 4;
    const int b = blockIdx.x >> 4;
    const int s0 = (blockIdx.x & 15) * 128;
    const int n0 = blockIdx.y * 128;
    const char* abase = (const char*)(A + ((size_t)b * SS + s0) * DD);
    const char* bbase = (const char*)Bm + (size_t)n0 * 1024;

    f32x4 acc[4][4];
    #pragma unroll
    for (int m = 0; m < 4; ++m)
        #pragma unroll
        for (int n = 0; n < 4; ++n) acc[m][n] = (f32x4)(0.0f);

    auto stage = [&](int db, int p) {
        #pragma unroll
        for (int j = 0; j < 4; ++j) {
            int x = (tid + j * 256) * 16;
            int gx = x ^ (((x >> 7) & 7) << 4);
            int row = gx >> 7, col = gx & 127;
            gl16(abase + (size_t)row * 1024 + p * 128 + col, (char*)As[db] + x);
            gl16(bbase + (size_t)row * 1024 + p * 128 + col, (char*)Bs[db] + x);
        }
    };

    stage(0, 0);
    for (int p = 0; p < 8; ++p) {
        if (p < 7) { stage((p + 1) & 1, p + 1); WAITV(8); }
        else       { WAITV(0); }
        BAR();
        const us* Ac = As[p & 1]; const us* Bc = Bs[p & 1];
        __builtin_amdgcn_s_setprio(1);
        #pragma unroll
        for (int kk = 0; kk < 2; ++kk) {
            bf16x8 af[4], bfr[4];
            #pragma unroll
            for (int m = 0; m < 4; ++m) af[m]  = ldfrag(Ac, 64 * wr + 16 * m + l15, kk * 32 + 8 * lg, 7);
            #pragma unroll
            for (int n = 0; n < 4; ++n) bfr[n] = ldfrag(Bc, 64 * wc + 16 * n + l15, kk * 32 + 8 * lg, 7);
            #pragma unroll
            for (int m = 0; m < 4; ++m)
                #pragma unroll
                for (int n = 0; n < 4; ++n)
                    acc[m][n] = MFMA16(af[m], bfr[n], acc[m][n]);
        }
        __builtin_amdgcn_s_setprio(0);
        BAR();
    }

    #pragma unroll
    for (int m = 0; m < 4; ++m) {
        #pragma unroll
        for (int n = 0; n < 4; ++n) {
            int col = n0 + 64 * wc + 16 * n + l15;
            float bia = bias[col];
            #pragma unroll
            for (int r = 0; r < 4; ++r) {
                int row = s0 + 64 * wr + 16 * m + 4 * lg + r;
                float v = acc[m][n][r] + bia;
                if (OUTMODE == 0)
                    ((us*)outp)[((size_t)b * SS + row) * DD + col] = f2b(v);
                else
                    ((float*)outp)[((size_t)row * BB + b) * DD + col] = v;
            }
        }
    }
}

// ---------------------------------------------------------------------------
// Flash attention v14: 4 BLOCKS/CU for TLP (the stall-bound fix).
//   QB=32 rows/block, 256 thr = 4 waves = 2 rg (16 rows) x 2 cg.  Grid 1024.
//   LDS = 40KB/block (ring-2 x 16KB + Pb 8KB) -> 4 blocks/CU; independent
//   barrier schedules overlap: one block's MFMA hides another's drain.
//   af[16] (Vt rows, all k) in regs (64 VGPR).  accv[4][4]=64.  ~180 total,
//   512-reg ceiling at this occupancy -> no spill by construction.
//   KV=64/step, 32 steps; 8 chunks/step of 16KB: 4 QK X[64t][128k] (256B rows)
//   + 4 PV XT[128e][64t] (128B rows).  4 gl16/thread/chunk; ring-2; wrap-issue
//   keeps 8 outstanding always -> WAITV(4) exact everywhere.
//   Row-sums via ones-B MFMA (accv-matching layout, no LDS exchange).
// ---------------------------------------------------------------------------
__global__ __launch_bounds__(256, 4) void k_attn(
        const us* __restrict__ Vtb, const us* __restrict__ Xb,
        const us* __restrict__ Xbt, us* __restrict__ Ob) {
    __shared__ __align__(16) us BUFS[2][8192];   // 2 x 16KB ring
    __shared__ __align__(16) us Pb[32 * 128];    // P [32 r][64 t used], 256B rows, 8KB

    const int tid = threadIdx.x;
    const int lane = tid & 63;
    const int w = tid >> 6;
    const int rg = w & 1;          // rows 16*rg .. +15
    const int cg = w >> 1;         // QK: t 32*cg..+32 ; PV: e-sub 64*cg..+64
    const int l15 = lane & 15, lg = lane >> 4;

    // XCD x owns batches {2x, 2x+1}; 64 s-tiles per batch.
    const int wg = blockIdx.x;
    const int b  = 2 * (wg & 7) + ((wg >> 3) & 1);
    const int s0 = (wg >> 4) * 32;

    const char* vbase  = (const char*)(Vtb + ((size_t)b * SS + s0) * DD);
    const char* xabase = (const char*)(Xb  + (size_t)b * SS * DD);
    const char* xtbase = (const char*)(Xbt + (size_t)b * DD * SS);

    // chunk c (8/step, 256 total): i=c&7, t0=(c>>3)*64.
    //   i<4:  X  [64 t-rows][128 k] (k-quarter i), 256B rows, swz (row&15)<<4
    //   i>=4: XT [128 e-rows][64 t] (e-window i-4), 128B rows, swz (row&7)<<4
    auto issue = [&](int cflat, us* dst0) {
        int c = cflat & 255;
        int i = c & 7, t0 = (c >> 3) << 6;
        char* dst = (char*)dst0;
        if (i < 4) {
            #pragma unroll
            for (int j = 0; j < 4; ++j) {
                int x = tid * 16 + j * 4096;
                int gx = x ^ (((x >> 8) & 15) << 4);
                int row = gx >> 8, col = gx & 255;
                gl16(xabase + (size_t)(t0 + row) * 1024 + i * 256 + col, dst + x);
            }
        } else {
            #pragma unroll
            for (int j = 0; j < 4; ++j) {
                int x = tid * 16 + j * 4096;
                int gx = x ^ (((x >> 7) & 7) << 4);
                int row = gx >> 7, col = gx & 127;
                gl16(xtbase + (size_t)((i - 4) * 128 + row) * (SS * 2)
                            + (size_t)t0 * 2 + col, dst + x);
            }
        }
    };

    // ---- prologue: Vt [32 rows][512 k] -> af regs, 2 rounds of 2x8KB subs --
    bf16x8 af[16];                 // af[kf] covers k = 32*kf, rows 16rg+l15
    #pragma unroll
    for (int half = 0; half < 2; ++half) {
        #pragma unroll
        for (int p = 0; p < 2; ++p) {
            #pragma unroll
            for (int j = 0; j < 2; ++j) {
                int x = tid * 16 + j * 4096;
                int gx = x ^ (((x >> 8) & 15) << 4);
                int row = gx >> 8, col = gx & 255;
                gl16(vbase + (size_t)row * 1024 + (2 * half + p) * 256 + col,
                     (char*)BUFS[0] + p * 8192 + x);
            }
        }
        WAITV(0); BAR();
        #pragma unroll
        for (int p = 0; p < 2; ++p)
            #pragma unroll
            for (int kk = 0; kk < 4; ++kk)
                af[4 * (2 * half + p) + kk] =
                    ldfrag8((const us*)BUFS[0] + p * 4096, 16 * rg + l15, 32 * kk + 8 * lg);
        WAITL(); BAR();
    }

    issue(0, BUFS[0]);
    issue(1, BUFS[1]);

    const short one_bf = (short)0x3F80;
    const bf16x8 ones = {one_bf, one_bf, one_bf, one_bf,
                         one_bf, one_bf, one_bf, one_bf};

    f32x4 accv[4][4];              // e = 128*p + 64*cg + 16*nt + l15
    #pragma unroll
    for (int p = 0; p < 4; ++p)
        #pragma unroll
        for (int nt = 0; nt < 4; ++nt) accv[p][nt] = (f32x4)(0.0f);
    f32x4 lsum = (f32x4)(0.0f);
    const int idx = 16 * rg + 4 * lg;

    for (int step = 0; step < 32; ++step) {
        const int cbase = step * 8;
        f32x4 sacc[2];
        sacc[0] = (f32x4)(0.0f); sacc[1] = (f32x4)(0.0f);

        // -------- QK: 4 phases (k-quarters), 8 MFMA each --------
        #pragma unroll
        for (int p = 0; p < 4; ++p) {
            const int c = cbase + p;
            WAITV(4); BAR();
            const us* sl = BUFS[c & 1];
            __builtin_amdgcn_s_setprio(1);
            #pragma unroll
            for (int kk = 0; kk < 4; ++kk)
                #pragma unroll
                for (int nt = 0; nt < 2; ++nt) {
                    bf16x8 bq = ldfrag8(sl, 32 * cg + 16 * nt + l15, 32 * kk + 8 * lg);
                    sacc[nt] = MFMA16(af[4 * p + kk], bq, sacc[nt]);
                }
            __builtin_amdgcn_s_setprio(0);
            BAR();
            issue(c + 2, BUFS[c & 1]);
        }

        // -------- softmax (static max): P = exp(s) -> Pb --------
        #pragma unroll
        for (int nt = 0; nt < 2; ++nt)
            #pragma unroll
            for (int ri = 0; ri < 4; ++ri)
                sacc[nt][ri] = __expf(sacc[nt][ri]);
        #pragma unroll
        for (int nt = 0; nt < 2; ++nt)
            #pragma unroll
            for (int ri = 0; ri < 4; ++ri) {
                int row = idx + ri;
                int col = 32 * cg + 16 * nt + l15;
                int off = ((row << 8) + (col << 1)) ^ ((row & 15) << 4);
                *(us*)((char*)Pb + off) = f2b(sacc[nt][ri]);
            }
        WAITL(); BAR();
        bf16x8 pa[2];
        #pragma unroll
        for (int kk = 0; kk < 2; ++kk)
            pa[kk] = ldfrag8(Pb, 16 * rg + l15, 32 * kk + 8 * lg);
        #pragma unroll
        for (int kk = 0; kk < 2; ++kk)
            lsum = MFMA16(pa[kk], ones, lsum);

        // -------- PV: 4 phases (e-windows), 8 MFMA each --------
        #pragma unroll
        for (int p = 0; p < 4; ++p) {
            const int c = cbase + 4 + p;
            WAITV(4); BAR();
            const us* sl = BUFS[c & 1];
            __builtin_amdgcn_s_setprio(1);
            #pragma unroll
            for (int kk = 0; kk < 2; ++kk)
                #pragma unroll
                for (int nt = 0; nt < 4; ++nt) {
                    bf16x8 bx = ldfrag(sl, 64 * cg + 16 * nt + l15, 32 * kk + 8 * lg, 7);
                    accv[p][nt] = MFMA16(pa[kk], bx, accv[p][nt]);
                }
            __builtin_amdgcn_s_setprio(0);
            BAR();
            issue(c + 2, BUFS[c & 1]);
        }
    }

    WAITV(0);
    // -------- epilogue: O' = accv / lsum (same row layout) -> bf16 --------
    us* orow = Ob + ((size_t)b * SS + s0) * DD;
    #pragma unroll
    for (int p = 0; p < 4; ++p)
        #pragma unroll
        for (int nt = 0; nt < 4; ++nt)
            #pragma unroll
            for (int ri = 0; ri < 4; ++ri) {
                int row = idx + ri;
                int e = 128 * p + 64 * cg + 16 * nt + l15;
                orow[(size_t)row * DD + e] = f2b(accv[p][nt][ri] / lsum[ri]);
            }
}

extern "C" void kernel_launch(void* const* d_in, const int* in_sizes, int n_in,
                              void* d_out, int out_size, void* d_ws, size_t ws_size,
                              hipStream_t stream) {
    const float* seq = (const float*)d_in[0];
    const float* Wv  = (const float*)d_in[1];
    const float* bv  = (const float*)d_in[2];
    const float* Wq  = (const float*)d_in[3];
    // d_in[4] = bq: softmax-row-constant -> unused
    const float* Wk  = (const float*)d_in[5];
    const float* bk  = (const float*)d_in[6];

    char* ws = (char*)d_ws;
    us*    Xb  = (us*)ws;                                  // [B][S][D] bf16, 32MB
    us*    Xbt = (us*)(ws + (size_t)33554432);             // [B][D][S] bf16, 32MB
    us*    Vtb = (us*)(ws + (size_t)67108864);             // [B][S][D] bf16, 32MB (reused as O')
    us*    Gt  = (us*)(ws + (size_t)100663296);            // [D][D] bf16
    us*    Wkb = (us*)(ws + (size_t)101187584);            // [D][D] bf16
    float* u   = (float*)(ws + (size_t)101711872);         // [D] fp32

    k_prep_x<<<dim3(8, 32, 16), 256, 0, stream>>>(seq, Xb, Xbt);
    k_prepG<<<dim3(8, 8), 256, 0, stream>>>(Wv, Wq, Gt);
    k_prepU<<<1, 512, 0, stream>>>(Wq, bv, u);
    k_prepW<<<256, 256, 0, stream>>>(Wk, Wkb);

    k_gemm<0><<<dim3(256, 4), 256, 0, stream>>>(Xb, Gt, u, (void*)Vtb);   // Vt = X*G + u
    k_attn<<<1024, 256, 0, stream>>>(Vtb, Xb, Xbt, Vtb);                  // O' over Vt
    k_gemm<1><<<dim3(256, 4), 256, 0, stream>>>(Vtb, Wkb, bk, d_out);     // out = O'*Wk^T + bk
}

// Round 13
// 369.329 us; speedup vs baseline: 1.8818x; 1.8818x over previous
//
#include <hip/hip_runtime.h>
#include <hip/hip_bf16.h>

#define SS 2048
#define BB 16
#define DD 512

typedef __attribute__((ext_vector_type(4))) float f32x4;
typedef __attribute__((ext_vector_type(8))) short bf16x8;
typedef __attribute__((ext_vector_type(4))) unsigned short us4;
typedef unsigned short us;

#define MFMA16(a,b,c) __builtin_amdgcn_mfma_f32_16x16x32_bf16((a),(b),(c),0,0,0)
#define BAR() __builtin_amdgcn_s_barrier()
#define WAITV(n) asm volatile("s_waitcnt vmcnt(" #n ")" ::: "memory")
#define WAITL()  asm volatile("s_waitcnt lgkmcnt(0)" ::: "memory")

__device__ __forceinline__ unsigned short f2b(float f) {
    union { float f; unsigned u; } v; v.f = f;
    unsigned r = v.u + 0x7FFFu + ((v.u >> 16) & 1u);
    return (unsigned short)(r >> 16);
}

// 256B-row LDS tile, 4-bit XOR swizzle (16-slot spread)
__device__ __forceinline__ bf16x8 ldfrag8(const us* base, int row, int kelem) {
    int off = (row << 8) + (kelem << 1);
    off ^= (row & 15) << 4;
    return *(const bf16x8*)((const char*)base + off);
}
// 128B-row (k_gemm)
__device__ __forceinline__ bf16x8 ldfrag(const us* base, int row, int kelem, int rowshift) {
    int off = (row << rowshift) + (kelem << 1);
    off ^= (row & 7) << 4;
    return *(const bf16x8*)((const char*)base + off);
}

__device__ __forceinline__ void gl16(const void* g, void* l) {
    __builtin_amdgcn_global_load_lds(
        (const __attribute__((address_space(1))) unsigned*)g,
        (__attribute__((address_space(3))) unsigned*)l, 16, 0, 0);
}

// ---------------------------------------------------------------------------
// Prep: seq [S][B][D] fp32 -> Xb [B][S][D] bf16 and Xbt [B][D][S] bf16.
// ---------------------------------------------------------------------------
__global__ __launch_bounds__(256) void k_prep_x(const float* __restrict__ seq,
        us* __restrict__ Xb, us* __restrict__ Xbt) {
    __shared__ __align__(16) char L[64 * 128];
    const int tid = threadIdx.x;
    const int d0 = blockIdx.x * 64, s0 = blockIdx.y * 64, b = blockIdx.z;
    {
        int r = tid >> 2, seg = (tid & 3) * 16;
        const float* src = seq + (size_t)(s0 + r) * (BB * DD) + (size_t)b * DD + d0 + seg;
        __align__(16) us vals[16];
        #pragma unroll
        for (int q = 0; q < 4; ++q) {
            f32x4 v = *(const f32x4*)(src + q * 4);
            vals[q*4+0] = f2b(v.x); vals[q*4+1] = f2b(v.y);
            vals[q*4+2] = f2b(v.z); vals[q*4+3] = f2b(v.w);
        }
        us* xo = Xb + ((size_t)b * SS + s0 + r) * DD + d0 + seg;
        *(bf16x8*)xo       = *(bf16x8*)&vals[0];
        *(bf16x8*)(xo + 8) = *(bf16x8*)&vals[8];
        #pragma unroll
        for (int j = 0; j < 16; ++j) {
            int d = seg + j;
            int addr = (d * 128 + r * 2) ^ ((d & 7) << 4);
            *(us*)(L + addr) = vals[j];
        }
    }
    __syncthreads();
    {
        int d = tid >> 2, sseg = (tid & 3) * 16;
        int c = (d & 7) << 4;
        int base = d * 128 + sseg * 2;
        bf16x8 h0 = *(bf16x8*)(L + (base ^ c));
        bf16x8 h1 = *(bf16x8*)(L + ((base + 16) ^ c));
        us* o = Xbt + ((size_t)b * DD + d0 + d) * SS + s0 + sseg;
        *(bf16x8*)o       = h0;
        *(bf16x8*)(o + 8) = h1;
    }
}

// ---------------------------------------------------------------------------
// Gt[p][i] = (1/sqrt(D)) * sum_a Wv[a,i] * Wq[a,p]
// ---------------------------------------------------------------------------
__global__ __launch_bounds__(256) void k_prepG(const float* __restrict__ Wv,
        const float* __restrict__ Wq, us* __restrict__ Gt) {
    __shared__ float Sq[32][64], Sv[32][64];
    const int tid = threadIdx.x;
    const int p0 = blockIdx.x * 64, i0 = blockIdx.y * 64;
    const int tp = tid & 15, ti = tid >> 4;
    float acc[4][4] = {};
    for (int a0 = 0; a0 < DD; a0 += 32) {
        #pragma unroll
        for (int j = 0; j < 2; ++j) {
            int slot = tid + j * 256;
            int row = slot >> 4, c4 = (slot & 15) * 4;
            *(f32x4*)&Sq[row][c4] = *(const f32x4*)(Wq + (size_t)(a0 + row) * DD + p0 + c4);
            *(f32x4*)&Sv[row][c4] = *(const f32x4*)(Wv + (size_t)(a0 + row) * DD + i0 + c4);
        }
        __syncthreads();
        for (int a = 0; a < 32; ++a) {
            f32x4 q = *(f32x4*)&Sq[a][tp * 4];
            f32x4 v = *(f32x4*)&Sv[a][ti * 4];
            #pragma unroll
            for (int x = 0; x < 4; ++x)
                #pragma unroll
                for (int y = 0; y < 4; ++y)
                    acc[x][y] += q[x] * v[y];
        }
        __syncthreads();
    }
    const float sc = 0.044194173824159216f;
    #pragma unroll
    for (int x = 0; x < 4; ++x)
        #pragma unroll
        for (int y = 0; y < 4; ++y)
            Gt[(size_t)(p0 + tp * 4 + x) * DD + i0 + ti * 4 + y] = f2b(acc[x][y] * sc);
}

// u[p] = (1/sqrt(D)) * sum_a bv[a] * Wq[a,p]
__global__ __launch_bounds__(512) void k_prepU(const float* __restrict__ Wq,
        const float* __restrict__ bv, float* __restrict__ u) {
    int p = threadIdx.x;
    float s = 0.f;
    for (int a0 = 0; a0 < DD; a0 += 8) {
        #pragma unroll
        for (int j = 0; j < 8; ++j)
            s += bv[a0 + j] * Wq[(size_t)(a0 + j) * DD + p];
    }
    u[p] = s * 0.044194173824159216f;
}

__global__ void k_prepW(const float* __restrict__ Wk, us* __restrict__ Wkb) {
    int i = (blockIdx.x * 256 + threadIdx.x) * 4;
    f32x4 v = *(const f32x4*)(Wk + i);
    us4 o; o.x = f2b(v.x); o.y = f2b(v.y); o.z = f2b(v.z); o.w = f2b(v.w);
    *(us4*)(Wkb + i) = o;
}

// ---------------------------------------------------------------------------
// bf16 GEMM: C[row,n] = sum_k A[row,k]*Bm[n,k] + bias[n]
// ---------------------------------------------------------------------------
template<int OUTMODE>
__global__ __launch_bounds__(256, 2) void k_gemm(
        const us* __restrict__ A, const us* __restrict__ Bm,
        const float* __restrict__ bias, void* __restrict__ outp) {
    __shared__ __align__(16) us As[2][128 * 64];
    __shared__ __align__(16) us Bs[2][128 * 64];
    const int tid = threadIdx.x;
    const int lane = tid & 63;
    const int w = tid >> 6;
    const int wr = w >> 1, wc = w & 1;
    const int l15 = lane & 15, lg = lane >> 4;
    const int b = blockIdx.x >> 4;
    const int s0 = (blockIdx.x & 15) * 128;
    const int n0 = blockIdx.y * 128;
    const char* abase = (const char*)(A + ((size_t)b * SS + s0) * DD);
    const char* bbase = (const char*)Bm + (size_t)n0 * 1024;

    f32x4 acc[4][4];
    #pragma unroll
    for (int m = 0; m < 4; ++m)
        #pragma unroll
        for (int n = 0; n < 4; ++n) acc[m][n] = (f32x4)(0.0f);

    auto stage = [&](int db, int p) {
        #pragma unroll
        for (int j = 0; j < 4; ++j) {
            int x = (tid + j * 256) * 16;
            int gx = x ^ (((x >> 7) & 7) << 4);
            int row = gx >> 7, col = gx & 127;
            gl16(abase + (size_t)row * 1024 + p * 128 + col, (char*)As[db] + x);
            gl16(bbase + (size_t)row * 1024 + p * 128 + col, (char*)Bs[db] + x);
        }
    };

    stage(0, 0);
    for (int p = 0; p < 8; ++p) {
        if (p < 7) { stage((p + 1) & 1, p + 1); WAITV(8); }
        else       { WAITV(0); }
        BAR();
        const us* Ac = As[p & 1]; const us* Bc = Bs[p & 1];
        __builtin_amdgcn_s_setprio(1);
        #pragma unroll
        for (int kk = 0; kk < 2; ++kk) {
            bf16x8 af[4], bfr[4];
            #pragma unroll
            for (int m = 0; m < 4; ++m) af[m]  = ldfrag(Ac, 64 * wr + 16 * m + l15, kk * 32 + 8 * lg, 7);
            #pragma unroll
            for (int n = 0; n < 4; ++n) bfr[n] = ldfrag(Bc, 64 * wc + 16 * n + l15, kk * 32 + 8 * lg, 7);
            #pragma unroll
            for (int m = 0; m < 4; ++m)
                #pragma unroll
                for (int n = 0; n < 4; ++n)
                    acc[m][n] = MFMA16(af[m], bfr[n], acc[m][n]);
        }
        __builtin_amdgcn_s_setprio(0);
        BAR();
    }

    #pragma unroll
    for (int m = 0; m < 4; ++m) {
        #pragma unroll
        for (int n = 0; n < 4; ++n) {
            int col = n0 + 64 * wc + 16 * n + l15;
            float bia = bias[col];
            #pragma unroll
            for (int r = 0; r < 4; ++r) {
                int row = s0 + 64 * wr + 16 * m + 4 * lg + r;
                float v = acc[m][n][r] + bia;
                if (OUTMODE == 0)
                    ((us*)outp)[((size_t)b * SS + row) * DD + col] = f2b(v);
                else
                    ((float*)outp)[((size_t)row * BB + b) * DD + col] = v;
            }
        }
    }
}

// ---------------------------------------------------------------------------
// Flash attention v15 = TLP (2 independent blocks/CU) + L2 locality
//   (one batch per XCD at a time).
//   QB=32 rows/block, 256 thr = 4 waves = 2 rg (16 rows) x 2 cg.  Grid 1024.
//   b = ((wg>>9)<<3)|(wg&7): first 512 resident blocks = batches 0..7, one
//   per XCD (64 blocks = 2/CU x 32 CUs, all the SAME batch -> 4MB hot set,
//   L2-resident); second round = batches 8..15.
//   LDS = 72KB (ring-2 x 32KB + Pb 8KB) -> exactly 2 blocks/CU; the two
//   blocks' barrier schedules are independent -> one's MFMA hides the
//   other's drain (the lockstep fix that r12 attempted without locality).
//   af[16] (Vt rows, all k) in regs (64 VGPR); accv 64; ~195 total, cap 256.
//   KV=128/step, 16 steps; 8 chunks/step of 32KB: 4 QK X[128t][128k] +
//   4 PV XT[128e][128t]; 256B rows, 4-bit swizzle; 8 gl16/thread/chunk;
//   ring-2; WAITV(8) exact.  Row-sums via ones-B MFMA (no LDS exchange).
// ---------------------------------------------------------------------------
__global__ __launch_bounds__(256, 2) void k_attn(
        const us* __restrict__ Vtb, const us* __restrict__ Xb,
        const us* __restrict__ Xbt, us* __restrict__ Ob) {
    __shared__ __align__(16) us BUFS[2][16384];  // 2 x 32KB ring
    __shared__ __align__(16) us Pb[32 * 128];    // P [32 r][128 t], 256B rows, 8KB

    const int tid = threadIdx.x;
    const int lane = tid & 63;
    const int w = tid >> 6;
    const int rg = w & 1;          // rows 16*rg .. +15
    const int cg = w >> 1;         // QK: t-half 64*cg ; PV: e-sub 64*cg
    const int l15 = lane & 15, lg = lane >> 4;

    // locality mapping: round = wg>>9 (0/1), XCD = wg&7, s-tile = (wg>>3)&63
    const int wg = blockIdx.x;
    const int b  = ((wg >> 9) << 3) | (wg & 7);
    const int s0 = ((wg >> 3) & 63) * 32;

    const char* vbase  = (const char*)(Vtb + ((size_t)b * SS + s0) * DD);
    const char* xabase = (const char*)(Xb  + (size_t)b * SS * DD);
    const char* xtbase = (const char*)(Xbt + (size_t)b * DD * SS);

    // chunk c (8/step, 128 total): i=c&7, t0=(c>>3)*128.
    //   i<4:  X  [128 t-rows][128 k] (k-quarter i), 256B rows, swz (row&15)<<4
    //   i>=4: XT [128 e-rows][128 t] (e-window i-4), 256B rows, same swizzle
    auto issue = [&](int cflat, us* dst0) {
        int c = cflat & 127;
        int i = c & 7, t0 = (c >> 3) << 7;
        char* dst = (char*)dst0;
        if (i < 4) {
            #pragma unroll
            for (int j = 0; j < 8; ++j) {
                int x = tid * 16 + j * 4096;
                int gx = x ^ (((x >> 8) & 15) << 4);
                int row = gx >> 8, col = gx & 255;
                gl16(xabase + (size_t)(t0 + row) * 1024 + i * 256 + col, dst + x);
            }
        } else {
            #pragma unroll
            for (int j = 0; j < 8; ++j) {
                int x = tid * 16 + j * 4096;
                int gx = x ^ (((x >> 8) & 15) << 4);
                int row = gx >> 8, col = gx & 255;
                gl16(xtbase + (size_t)((i - 4) * 128 + row) * (SS * 2)
                            + (size_t)t0 * 2 + col, dst + x);
            }
        }
    };

    // ---- prologue: Vt [32 rows][512 k] -> af regs via 4 x 8KB sub-chunks --
    #pragma unroll
    for (int p = 0; p < 4; ++p) {
        #pragma unroll
        for (int j = 0; j < 2; ++j) {
            int x = tid * 16 + j * 4096;
            int gx = x ^ (((x >> 8) & 15) << 4);
            int row = gx >> 8, col = gx & 255;
            gl16(vbase + (size_t)row * 1024 + p * 256 + col,
                 (char*)BUFS[0] + p * 8192 + x);
        }
    }
    WAITV(0); BAR();
    bf16x8 af[16];                 // af[4p+kk] covers k = 128p + 32kk
    #pragma unroll
    for (int p = 0; p < 4; ++p)
        #pragma unroll
        for (int kk = 0; kk < 4; ++kk)
            af[4 * p + kk] = ldfrag8((const us*)BUFS[0] + p * 4096,
                                     16 * rg + l15, 32 * kk + 8 * lg);
    WAITL(); BAR();

    issue(0, BUFS[0]);
    issue(1, BUFS[1]);

    const short one_bf = (short)0x3F80;
    const bf16x8 ones = {one_bf, one_bf, one_bf, one_bf,
                         one_bf, one_bf, one_bf, one_bf};

    f32x4 accv[4][4];              // e = 128*p + 64*cg + 16*nt + l15
    #pragma unroll
    for (int p = 0; p < 4; ++p)
        #pragma unroll
        for (int nt = 0; nt < 4; ++nt) accv[p][nt] = (f32x4)(0.0f);
    f32x4 lsum = (f32x4)(0.0f);
    const int idx = 16 * rg + 4 * lg;

    for (int step = 0; step < 16; ++step) {
        const int cbase = step * 8;
        f32x4 sacc[4];
        #pragma unroll
        for (int nt = 0; nt < 4; ++nt) sacc[nt] = (f32x4)(0.0f);

        // -------- QK: 4 phases (k-quarters), 16 MFMA/wave each --------
        #pragma unroll
        for (int p = 0; p < 4; ++p) {
            const int c = cbase + p;
            WAITV(8); BAR();
            const us* sl = BUFS[c & 1];
            __builtin_amdgcn_s_setprio(1);
            #pragma unroll
            for (int kk = 0; kk < 4; ++kk)
                #pragma unroll
                for (int nt = 0; nt < 4; ++nt) {
                    bf16x8 bq = ldfrag8(sl, 64 * cg + 16 * nt + l15, 32 * kk + 8 * lg);
                    sacc[nt] = MFMA16(af[4 * p + kk], bq, sacc[nt]);
                }
            __builtin_amdgcn_s_setprio(0);
            BAR();
            issue(c + 2, BUFS[c & 1]);
        }

        // -------- softmax (static max): P = exp(s) -> Pb --------
        #pragma unroll
        for (int nt = 0; nt < 4; ++nt)
            #pragma unroll
            for (int ri = 0; ri < 4; ++ri)
                sacc[nt][ri] = __expf(sacc[nt][ri]);
        #pragma unroll
        for (int nt = 0; nt < 4; ++nt)
            #pragma unroll
            for (int ri = 0; ri < 4; ++ri) {
                int row = idx + ri;
                int col = 64 * cg + 16 * nt + l15;
                int off = ((row << 8) + (col << 1)) ^ ((row & 15) << 4);
                *(us*)((char*)Pb + off) = f2b(sacc[nt][ri]);
            }
        WAITL(); BAR();
        bf16x8 pa[4];
        #pragma unroll
        for (int kk = 0; kk < 4; ++kk)
            pa[kk] = ldfrag8(Pb, 16 * rg + l15, 32 * kk + 8 * lg);
        #pragma unroll
        for (int kk = 0; kk < 4; ++kk)
            lsum = MFMA16(pa[kk], ones, lsum);

        // -------- PV: 4 phases (e-windows), 16 MFMA/wave each --------
        #pragma unroll
        for (int p = 0; p < 4; ++p) {
            const int c = cbase + 4 + p;
            WAITV(8); BAR();
            const us* sl = BUFS[c & 1];
            __builtin_amdgcn_s_setprio(1);
            #pragma unroll
            for (int kk = 0; kk < 4; ++kk)
                #pragma unroll
                for (int nt = 0; nt < 4; ++nt) {
                    bf16x8 bx = ldfrag8(sl, 64 * cg + 16 * nt + l15, 32 * kk + 8 * lg);
                    accv[p][nt] = MFMA16(pa[kk], bx, accv[p][nt]);
                }
            __builtin_amdgcn_s_setprio(0);
            BAR();
            issue(c + 2, BUFS[c & 1]);
        }
    }

    WAITV(0);
    // -------- epilogue: O' = accv / lsum (same row layout) -> bf16 --------
    us* orow = Ob + ((size_t)b * SS + s0) * DD;
    #pragma unroll
    for (int p = 0; p < 4; ++p)
        #pragma unroll
        for (int nt = 0; nt < 4; ++nt)
            #pragma unroll
            for (int ri = 0; ri < 4; ++ri) {
                int row = idx + ri;
                int e = 128 * p + 64 * cg + 16 * nt + l15;
                orow[(size_t)row * DD + e] = f2b(accv[p][nt][ri] / lsum[ri]);
            }
}

extern "C" void kernel_launch(void* const* d_in, const int* in_sizes, int n_in,
                              void* d_out, int out_size, void* d_ws, size_t ws_size,
                              hipStream_t stream) {
    const float* seq = (const float*)d_in[0];
    const float* Wv  = (const float*)d_in[1];
    const float* bv  = (const float*)d_in[2];
    const float* Wq  = (const float*)d_in[3];
    // d_in[4] = bq: softmax-row-constant -> unused
    const float* Wk  = (const float*)d_in[5];
    const float* bk  = (const float*)d_in[6];

    char* ws = (char*)d_ws;
    us*    Xb  = (us*)ws;                                  // [B][S][D] bf16, 32MB
    us*    Xbt = (us*)(ws + (size_t)33554432);             // [B][D][S] bf16, 32MB
    us*    Vtb = (us*)(ws + (size_t)67108864);             // [B][S][D] bf16, 32MB (reused as O')
    us*    Gt  = (us*)(ws + (size_t)100663296);            // [D][D] bf16
    us*    Wkb = (us*)(ws + (size_t)101187584);            // [D][D] bf16
    float* u   = (float*)(ws + (size_t)101711872);         // [D] fp32

    k_prep_x<<<dim3(8, 32, 16), 256, 0, stream>>>(seq, Xb, Xbt);
    k_prepG<<<dim3(8, 8), 256, 0, stream>>>(Wv, Wq, Gt);
    k_prepU<<<1, 512, 0, stream>>>(Wq, bv, u);
    k_prepW<<<256, 256, 0, stream>>>(Wk, Wkb);

    k_gemm<0><<<dim3(256, 4), 256, 0, stream>>>(Xb, Gt, u, (void*)Vtb);   // Vt = X*G + u
    k_attn<<<1024, 256, 0, stream>>>(Vtb, Xb, Xbt, Vtb);                  // O' over Vt
    k_gemm<1><<<dim3(256, 4), 256, 0, stream>>>(Vtb, Wkb, bk, d_out);     // out = O'*Wk^T + bk
}